// Round 11
// baseline (305.962 us; speedup 1.0000x reference)
//
#include <hip/hip_runtime.h>
#include <hip/hip_fp16.h>
#include <math.h>

#define N_NODES 50000
#define N_EDGES 800000
#define E_TOT   850000          // edges + self loops
#define NEG_SLOPE 0.2f
#define SRC_SPLIT 25000         // 2 src ranges -> 3.2MB H slice fits per-XCD L2
#define N2 (2 * N_NODES)        // (dst, range) buckets
#define NB2 98                  // ceil(N2 / 1024)
#define DEG_BLOCKS ((E_TOT + 255) / 256)      // 3321
#define GEMM_BLOCKS ((N_NODES + 15) / 16)     // 3125  (DO=64 -> NPB=16)

// ===========================================================================
// CSR over (dst, src-range) buckets; dst-segments stay contiguous with an
// internal range boundary: node d owns [offs2[2d], offs2[2d+2]).
// ===========================================================================
__global__ void csr_init(int* deg2) {
    int i = blockIdx.x * blockDim.x + threadIdx.x;
    if (i < N2) deg2[i] = 0;
}

// merged: blocks [0, DEG_BLOCKS) do degree+rank; rest do layer-1 GEMM+proj
__global__ void degree_gemm(const int* __restrict__ src, const int* __restrict__ dst,
                            int* __restrict__ deg2, int* __restrict__ rank,
                            const float* __restrict__ X, const float* __restrict__ W,
                            const float* __restrict__ a_src, const float* __restrict__ a_dst,
                            __half* __restrict__ Hh, float* __restrict__ ssrc,
                            float* __restrict__ sdst) {
    __shared__ float sW[64 * 64];
    __shared__ float sX[16][65];
    if (blockIdx.x < DEG_BLOCKS) {
        int e = blockIdx.x * 256 + threadIdx.x;
        if (e >= E_TOT) return;
        int s, d;
        if (e < N_EDGES) { s = src[e]; d = dst[e]; } else { s = e - N_EDGES; d = s; }
        int rng = (s >= SRC_SPLIT) ? 1 : 0;
        rank[e] = atomicAdd(&deg2[2 * d + rng], 1);
        return;
    }
    // ---- layer-1 GEMM (DI=DO=64), 4 channels/thread ----
    const int bx = blockIdx.x - DEG_BLOCKS;
    const int tid = threadIdx.x;
    for (int i = tid; i < 64 * 64 / 4; i += 256)
        ((float4*)sW)[i] = ((const float4*)W)[i];
    const int base = bx * 16;
    for (int i = tid; i < 16 * 64; i += 256) {
        int r = i / 64, col = i % 64;
        int node = base + r;
        sX[r][col] = (node < N_NODES) ? X[(long)node * 64 + col] : 0.0f;
    }
    __syncthreads();
    const int cq = tid % 16;
    const int g  = tid / 16;
    const int node = base + g;
    if (node >= N_NODES) return;
    float ax = 0.0f, ay = 0.0f, az = 0.0f, aw = 0.0f;
    const float4* sW4 = (const float4*)sW;
#pragma unroll
    for (int k = 0; k < 64; k++) {
        float xv = sX[g][k];
        float4 w4 = sW4[k * 16 + cq];
        ax = fmaf(xv, w4.x, ax); ay = fmaf(xv, w4.y, ay);
        az = fmaf(xv, w4.z, az); aw = fmaf(xv, w4.w, aw);
    }
    union { uint2 u; __half2 h2[2]; } pk;
    pk.h2[0] = __float22half2_rn(make_float2(ax, ay));
    pk.h2[1] = __float22half2_rn(make_float2(az, aw));
    ((uint2*)(Hh + (long)node * 64))[cq] = pk.u;
    float4 as4 = ((const float4*)a_src)[cq];
    float4 ad4 = ((const float4*)a_dst)[cq];
    float ps = ax * as4.x + ay * as4.y + az * as4.z + aw * as4.w;
    float pd = ax * ad4.x + ay * ad4.y + az * ad4.z + aw * ad4.w;
#pragma unroll
    for (int m = 8; m >= 1; m >>= 1) {
        ps += __shfl_xor(ps, m, 16);
        pd += __shfl_xor(pd, m, 16);
    }
    if (cq == 0) { ssrc[node] = ps; sdst[node] = pd; }
}

// --- hierarchical exclusive scan of deg2[0..N2) -> offs2[0..N2] -----------
__global__ void scan_p1(const int* __restrict__ deg2, int* __restrict__ bsum) {
    __shared__ int red[1024];
    int i = blockIdx.x * 1024 + threadIdx.x;
    red[threadIdx.x] = (i < N2) ? deg2[i] : 0;
    __syncthreads();
    for (int off = 512; off >= 1; off >>= 1) {
        if (threadIdx.x < off) red[threadIdx.x] += red[threadIdx.x + off];
        __syncthreads();
    }
    if (threadIdx.x == 0) bsum[blockIdx.x] = red[0];
}

__global__ void scan_p3(const int* __restrict__ deg2, const int* __restrict__ bsum,
                        int* __restrict__ offs2) {
    __shared__ int s[1024];
    __shared__ int sb[128];
    int i = blockIdx.x * 1024 + threadIdx.x;
    int v = (i < N2) ? deg2[i] : 0;
    s[threadIdx.x] = v;
    if (threadIdx.x < 128) sb[threadIdx.x] = (threadIdx.x < NB2) ? bsum[threadIdx.x] : 0;
    __syncthreads();
    // scan the 98 block sums (128-entry Hillis-Steele)
    for (int off = 1; off < 128; off <<= 1) {
        int u = (threadIdx.x < 128 && threadIdx.x >= off) ? sb[threadIdx.x - off] : 0;
        __syncthreads();
        if (threadIdx.x < 128) sb[threadIdx.x] += u;
        __syncthreads();
    }
    if (blockIdx.x == NB2 - 1 && threadIdx.x == 0) offs2[N2] = sb[NB2 - 1];
    const int bofs = (blockIdx.x == 0) ? 0 : sb[blockIdx.x - 1];
    // scan this block's 1024 entries
    for (int off = 1; off < 1024; off <<= 1) {
        int u = (threadIdx.x >= off) ? s[threadIdx.x - off] : 0;
        __syncthreads();
        s[threadIdx.x] += u;
        __syncthreads();
    }
    if (i < N2) offs2[i] = bofs + s[threadIdx.x] - v;            // exclusive
}

// no atomics: pos = offs2[bucket] + rank[e]
__global__ void csr_fill(const int* __restrict__ src, const int* __restrict__ dst,
                         const int* __restrict__ rank, const int* __restrict__ offs2,
                         int* __restrict__ csr_src) {
    int e = blockIdx.x * blockDim.x + threadIdx.x;
    if (e >= E_TOT) return;
    int s, d;
    if (e < N_EDGES) { s = src[e]; d = dst[e]; } else { s = e - N_EDGES; d = s; }
    int rng = (s >= SRC_SPLIT) ? 1 : 0;
    csr_src[offs2[2 * d + rng] + rank[e]] = s;
}

// ===========================================================================
// Fused gather(+softmax)+bias(+relu)(+next GEMM+proj). PASSES=2: process all
// nodes' range-0 edges first, then range-1 — with the fixed co-resident
// 1024-block grid the chip-wide hot H slice per phase is ~3.2MB -> L2-hits.
// ===========================================================================
template<int DIN, int DOUT, int PASSES>
__launch_bounds__(256, 4)
__global__ void gather_gemm(const __half* __restrict__ Hh_in,
                            const float* __restrict__ ssrc_in,
                            const float* __restrict__ sdst_in,
                            const int* __restrict__ offs2,
                            const int* __restrict__ csr_src,
                            const float* __restrict__ bias_in,
                            int relu_o, float* __restrict__ extra_out,
                            const float* __restrict__ W2,
                            const float* __restrict__ a_src2,
                            const float* __restrict__ a_dst2,
                            __half* __restrict__ Hh_out,
                            float* __restrict__ ssrc2, float* __restrict__ sdst2) {
    constexpr int G = DIN / 4;                       // lanes per node group
    constexpr int GPB = 256 / G;                     // groups per block
    constexpr int NG = 1024 * GPB;                   // total groups (grid=1024)
    constexpr int ITER = (N_NODES + NG - 1) / NG;    // nodes per group
    constexpr int LDSW = (DOUT > 0) ? DIN * DOUT : 1;
    __shared__ float sW[LDSW];
    if constexpr (DOUT > 0) {
        for (int i = threadIdx.x; i < DIN * DOUT / 4; i += 256)
            ((float4*)sW)[i] = ((const float4*)W2)[i];
        __syncthreads();
    }
    const int gid = blockIdx.x * GPB + threadIdx.x / G;
    const int r = threadIdx.x % G;
    const uint2* H2 = (const uint2*)Hh_in;

    float4 acc[ITER];
    float  den[ITER];
    float  sdv[ITER];
#pragma unroll
    for (int it = 0; it < ITER; it++) {
        acc[it] = make_float4(0.0f, 0.0f, 0.0f, 0.0f);
        den[it] = 0.0f;
        int node = gid + it * NG;
        sdv[it] = (node < N_NODES) ? sdst_in[node] : 0.0f;
    }

#pragma unroll
    for (int p = 0; p < PASSES; p++) {
#pragma unroll
        for (int it = 0; it < ITER; it++) {
            const int node = gid + it * NG;
            if (node >= N_NODES) continue;
            int rbeg, rend;
            if constexpr (PASSES == 2) {
                rbeg = offs2[2 * node + p];
                rend = offs2[2 * node + p + 1];
            } else {
                rbeg = offs2[2 * node];
                rend = offs2[2 * node + 2];
            }
            const float sdvv = sdv[it];
            for (int cb = rbeg; cb < rend; cb += G) {
                const int cnt = min(G, rend - cb);
                int s0 = 0; float ex = 0.0f;
                if (r < cnt) {
                    s0 = csr_src[cb + r];
                    float v = ssrc_in[s0] + sdvv;
                    v = (v > 0.0f) ? v : NEG_SLOPE * v;      // leaky relu
                    ex = __expf(v);
                }
                den[it] += ex;
                int j = 0;
                for (; j + 4 <= cnt; j += 4) {
                    int   sa = __shfl(s0, j,     G), sb = __shfl(s0, j + 1, G);
                    int   sc = __shfl(s0, j + 2, G), sd2 = __shfl(s0, j + 3, G);
                    float ea = __shfl(ex, j,     G), eb = __shfl(ex, j + 1, G);
                    float ec = __shfl(ex, j + 2, G), ed = __shfl(ex, j + 3, G);
                    union { uint2 u; __half2 h2[2]; } ua, ub, uc, ud;
                    ua.u = H2[(long)sa * G + r];
                    ub.u = H2[(long)sb * G + r];
                    uc.u = H2[(long)sc * G + r];
                    ud.u = H2[(long)sd2 * G + r];
                    float2 a0 = __half22float2(ua.h2[0]), a1 = __half22float2(ua.h2[1]);
                    float2 b0 = __half22float2(ub.h2[0]), b1 = __half22float2(ub.h2[1]);
                    float2 c0 = __half22float2(uc.h2[0]), c1 = __half22float2(uc.h2[1]);
                    float2 d0 = __half22float2(ud.h2[0]), d1 = __half22float2(ud.h2[1]);
                    acc[it].x = fmaf(ea, a0.x, acc[it].x); acc[it].y = fmaf(ea, a0.y, acc[it].y);
                    acc[it].z = fmaf(ea, a1.x, acc[it].z); acc[it].w = fmaf(ea, a1.y, acc[it].w);
                    acc[it].x = fmaf(eb, b0.x, acc[it].x); acc[it].y = fmaf(eb, b0.y, acc[it].y);
                    acc[it].z = fmaf(eb, b1.x, acc[it].z); acc[it].w = fmaf(eb, b1.y, acc[it].w);
                    acc[it].x = fmaf(ec, c0.x, acc[it].x); acc[it].y = fmaf(ec, c0.y, acc[it].y);
                    acc[it].z = fmaf(ec, c1.x, acc[it].z); acc[it].w = fmaf(ec, c1.y, acc[it].w);
                    acc[it].x = fmaf(ed, d0.x, acc[it].x); acc[it].y = fmaf(ed, d0.y, acc[it].y);
                    acc[it].z = fmaf(ed, d1.x, acc[it].z); acc[it].w = fmaf(ed, d1.y, acc[it].w);
                }
                for (; j < cnt; j++) {
                    int   sa = __shfl(s0, j, G);
                    float ea = __shfl(ex, j, G);
                    union { uint2 u; __half2 h2[2]; } ua;
                    ua.u = H2[(long)sa * G + r];
                    float2 a0 = __half22float2(ua.h2[0]), a1 = __half22float2(ua.h2[1]);
                    acc[it].x = fmaf(ea, a0.x, acc[it].x); acc[it].y = fmaf(ea, a0.y, acc[it].y);
                    acc[it].z = fmaf(ea, a1.x, acc[it].z); acc[it].w = fmaf(ea, a1.y, acc[it].w);
                }
            }
        }
    }

    // ---- epilogue + optional fused next-layer GEMM, per node iteration ----
#pragma unroll
    for (int it = 0; it < ITER; it++) {
        const int node = gid + it * NG;
        const bool valid = (node < N_NODES);
        float dn = den[it];
#pragma unroll
        for (int m = G / 2; m >= 1; m >>= 1) dn += __shfl_xor(dn, m, G);
        float inv = 1.0f / (dn + 1e-16f);
        float4 b4 = ((const float4*)bias_in)[r];
        float4 o;
        o.x = acc[it].x * inv + b4.x; o.y = acc[it].y * inv + b4.y;
        o.z = acc[it].z * inv + b4.z; o.w = acc[it].w * inv + b4.w;
        if (valid && extra_out) ((float4*)extra_out)[(long)node * G + r] = o;
        if (relu_o) {
            o.x = fmaxf(o.x, 0.0f); o.y = fmaxf(o.y, 0.0f);
            o.z = fmaxf(o.z, 0.0f); o.w = fmaxf(o.w, 0.0f);
        }
        if constexpr (DOUT > 0) {
            constexpr int C = DOUT / G;              // output channels per lane
            float acc2[C];
#pragma unroll
            for (int c = 0; c < C; c++) acc2[c] = 0.0f;
            const int cbase = r * C;
#pragma unroll
            for (int kb = 0; kb < G; kb++) {
                float4 o4;
                o4.x = __shfl(o.x, kb, G);
                o4.y = __shfl(o.y, kb, G);
                o4.z = __shfl(o.z, kb, G);
                o4.w = __shfl(o.w, kb, G);
                const float* wr = &sW[(4 * kb) * DOUT + cbase];
#pragma unroll
                for (int c = 0; c < C; c++) acc2[c] = fmaf(o4.x, wr[c], acc2[c]);
                wr += DOUT;
#pragma unroll
                for (int c = 0; c < C; c++) acc2[c] = fmaf(o4.y, wr[c], acc2[c]);
                wr += DOUT;
#pragma unroll
                for (int c = 0; c < C; c++) acc2[c] = fmaf(o4.z, wr[c], acc2[c]);
                wr += DOUT;
#pragma unroll
                for (int c = 0; c < C; c++) acc2[c] = fmaf(o4.w, wr[c], acc2[c]);
            }
            float ps = 0.0f, pd = 0.0f;
#pragma unroll
            for (int c = 0; c < C; c++) {
                ps = fmaf(acc2[c], a_src2[cbase + c], ps);
                pd = fmaf(acc2[c], a_dst2[cbase + c], pd);
            }
#pragma unroll
            for (int m = G / 2; m >= 1; m >>= 1) {
                ps += __shfl_xor(ps, m, G);
                pd += __shfl_xor(pd, m, G);
            }
            if (valid) {
                union { unsigned int u1; uint2 u2; uint4 u4; __half2 h[C / 2]; } pk;
#pragma unroll
                for (int c = 0; c < C; c += 2)
                    pk.h[c / 2] = __float22half2_rn(make_float2(acc2[c], acc2[c + 1]));
                char* dp = (char*)(Hh_out + (long)node * DOUT + cbase);
                if constexpr (C == 2) *(unsigned int*)dp = pk.u1;
                else if constexpr (C == 4) *(uint2*)dp = pk.u2;
                else                        *(uint4*)dp = pk.u4;
                if (r == 0) { ssrc2[node] = ps; sdst2[node] = pd; }
            }
        }
    }
}

extern "C" void kernel_launch(void* const* d_in, const int* in_sizes, int n_in,
                              void* d_out, int out_size, void* d_ws, size_t ws_size,
                              hipStream_t stream) {
    const float* x  = (const float*)d_in[0];
    const int*   ei = (const int*)d_in[1];

    const float* w1  = (const float*)d_in[2];
    const float* as1 = (const float*)d_in[3];
    const float* ad1 = (const float*)d_in[4];
    const float* b1  = (const float*)d_in[5];
    const float* w2  = (const float*)d_in[6];
    const float* as2 = (const float*)d_in[7];
    const float* ad2 = (const float*)d_in[8];
    const float* b2  = (const float*)d_in[9];
    const float* w3  = (const float*)d_in[10];
    const float* as3 = (const float*)d_in[11];
    const float* ad3 = (const float*)d_in[12];
    const float* b3  = (const float*)d_in[13];
    const float* w4  = (const float*)d_in[14];
    const float* as4 = (const float*)d_in[15];
    const float* ad4 = (const float*)d_in[16];
    const float* b4  = (const float*)d_in[17];

    float* out_final = (float*)d_out;                 // [N, 64]
    float* out_h     = (float*)d_out + N_NODES * 64;  // [N, 32] (layer2 pre-relu)

    // workspace layout
    float* ws    = (float*)d_ws;
    __half* Hh_a = (__half*)ws;                 // N*64 halves
    __half* Hh_b = (__half*)(ws + N_NODES * 32);
    float* SS_a  = ws + 2 * N_NODES * 32;       // N
    float* SD_a  = SS_a + N_NODES;              // N
    float* SS_b  = SD_a + N_NODES;              // N
    float* SD_b  = SS_b + N_NODES;              // N
    int* deg2    = (int*)(SD_b + N_NODES);      // 2N
    int* rank    = deg2 + N2;                   // E_TOT
    int* offs2   = rank + E_TOT;                // 2N+1
    int* csr_src = offs2 + N2 + 1;              // E_TOT
    int* bsum    = csr_src + E_TOT;             // NB2

    const int* src = ei;                // edge_index row 0
    const int* dst = ei + N_EDGES;      // edge_index row 1

    // --- build (dst, src-range) CSR; layer-1 GEMM merged into degree pass ---
    csr_init<<<(N2 + 255) / 256, 256, 0, stream>>>(deg2);
    degree_gemm<<<DEG_BLOCKS + GEMM_BLOCKS, 256, 0, stream>>>(
        src, dst, deg2, rank, x, w1, as1, ad1, Hh_a, SS_a, SD_a);
    scan_p1<<<NB2, 1024, 0, stream>>>(deg2, bsum);
    scan_p3<<<NB2, 1024, 0, stream>>>(deg2, bsum, offs2);
    csr_fill<<<(E_TOT + 255) / 256, 256, 0, stream>>>(src, dst, rank, offs2, csr_src);

    // --- 4 fused gather[+next-GEMM] stages (fixed 1024-block resident grid) ---
    // agg L1 (+b1, relu) -> gemm W2 -> L2 frags          [H 6.4MB -> 2 passes]
    gather_gemm<64, 32, 2><<<1024, 256, 0, stream>>>(
        Hh_a, SS_a, SD_a, offs2, csr_src, b1, 1, nullptr,
        w2, as2, ad2, Hh_b, SS_b, SD_b);
    // agg L2 (+b2) -> out_h (pre-relu), relu -> gemm W3  [H 3.2MB -> 1 pass]
    gather_gemm<32, 64, 1><<<1024, 256, 0, stream>>>(
        Hh_b, SS_b, SD_b, offs2, csr_src, b2, 1, out_h,
        w3, as3, ad3, Hh_a, SS_a, SD_a);
    // agg L3 (+b3, relu) -> gemm W4 -> L4 frags          [2 passes]
    gather_gemm<64, 64, 2><<<1024, 256, 0, stream>>>(
        Hh_a, SS_a, SD_a, offs2, csr_src, b3, 1, nullptr,
        w4, as4, ad4, Hh_b, SS_b, SD_b);
    // agg L4 (+b4) -> out_final (no relu, no gemm)       [2 passes]
    gather_gemm<64, 0, 2><<<1024, 256, 0, stream>>>(
        Hh_b, SS_b, SD_b, offs2, csr_src, b4, 0, out_final,
        nullptr, nullptr, nullptr, nullptr, nullptr, nullptr);
}

// Round 12
// 271.916 us; speedup vs baseline: 1.1252x; 1.1252x over previous
//
#include <hip/hip_runtime.h>
#include <hip/hip_fp16.h>
#include <math.h>

#define N_NODES 50000
#define N_EDGES 800000
#define E_TOT   850000          // edges + self loops
#define NEG_SLOPE 0.2f
#define NB_SCAN 49              // ceil(N_NODES / 1024)

typedef unsigned short u16;     // N_NODES < 65536: src ids and ranks fit in 16b

// ===========================================================================
// CSR-by-dst construction (once per call; dst indices shared by all 4 layers)
// ===========================================================================
__global__ void csr_init(int* deg) {
    int i = blockIdx.x * blockDim.x + threadIdx.x;
    if (i < N_NODES) deg[i] = 0;
}

// degree pass also records each edge's arrival rank (atomicAdd return value)
__global__ void csr_degree(const int* __restrict__ dst, int* __restrict__ deg,
                           u16* __restrict__ rank) {
    int e = blockIdx.x * blockDim.x + threadIdx.x;
    if (e >= E_TOT) return;
    int d = (e < N_EDGES) ? dst[e] : (e - N_EDGES);
    rank[e] = (u16)atomicAdd(&deg[d], 1);
}

// --- hierarchical exclusive scan of deg[0..N) -> offs[0..N] ---------------
__global__ void scan_p1(const int* __restrict__ deg, int* __restrict__ bsum) {
    __shared__ int red[1024];
    int i = blockIdx.x * 1024 + threadIdx.x;
    red[threadIdx.x] = (i < N_NODES) ? deg[i] : 0;
    __syncthreads();
    for (int off = 512; off >= 1; off >>= 1) {
        if (threadIdx.x < off) red[threadIdx.x] += red[threadIdx.x + off];
        __syncthreads();
    }
    if (threadIdx.x == 0) bsum[blockIdx.x] = red[0];
}

// p3 derives its own block offset from bsum (wave-scan per block).
__global__ void scan_p3(const int* __restrict__ deg, const int* __restrict__ bsum,
                        int* __restrict__ offs) {
    __shared__ int s[1024];
    __shared__ int bofs;
    int i = blockIdx.x * 1024 + threadIdx.x;
    int v = (i < N_NODES) ? deg[i] : 0;
    s[threadIdx.x] = v;
    if (threadIdx.x < 64) {
        int d = (threadIdx.x < NB_SCAN) ? bsum[threadIdx.x] : 0;
        int p = d;
        for (int off = 1; off < 64; off <<= 1) {
            int u = __shfl_up(p, off, 64);
            if ((int)threadIdx.x >= off) p += u;
        }
        if ((int)threadIdx.x == (int)blockIdx.x) bofs = p - d;   // exclusive block prefix
        if (blockIdx.x == NB_SCAN - 1 && threadIdx.x == NB_SCAN - 1)
            offs[N_NODES] = p;                                   // grand total
    }
    __syncthreads();
    for (int off = 1; off < 1024; off <<= 1) {
        int u = (threadIdx.x >= off) ? s[threadIdx.x - off] : 0;
        __syncthreads();
        s[threadIdx.x] += u;
        __syncthreads();
    }
    if (i < N_NODES) offs[i] = bofs + s[threadIdx.x] - v;        // exclusive
}

// no atomics: pos = offs[d] + rank[e] (offs is 200KB -> L2-resident)
__global__ void csr_fill(const int* __restrict__ src, const int* __restrict__ dst,
                         const u16* __restrict__ rank, const int* __restrict__ offs,
                         u16* __restrict__ csr_src) {
    int e = blockIdx.x * blockDim.x + threadIdx.x;
    if (e >= E_TOT) return;
    int s, d;
    if (e < N_EDGES) { s = src[e]; d = dst[e]; } else { s = e - N_EDGES; d = s; }
    csr_src[offs[d] + rank[e]] = (u16)s;
}

// ===========================================================================
// Layer-1 GEMM: h = X @ W fused with attention projections (reads global x).
// ===========================================================================
template<int DI, int DO>
__global__ void gemm_proj(const float* __restrict__ X, const float* __restrict__ W,
                          const float* __restrict__ a_src, const float* __restrict__ a_dst,
                          __half* __restrict__ Hh, float* __restrict__ ssrc,
                          float* __restrict__ sdst) {
    const int TPN = DO / 4;          // threads per node
    const int NPB = 256 / TPN;       // nodes per block
    __shared__ float sW[DI * DO];
    __shared__ float sX[NPB][DI + 1];          // +1: break broadcast bank aliasing
    const int tid = threadIdx.x;
    for (int i = tid; i < DI * DO / 4; i += 256)
        ((float4*)sW)[i] = ((const float4*)W)[i];
    const int base = blockIdx.x * NPB;
    for (int i = tid; i < NPB * DI; i += 256) {
        int r = i / DI, col = i % DI;
        int node = base + r;
        sX[r][col] = (node < N_NODES) ? X[(long)node * DI + col] : 0.0f;
    }
    __syncthreads();
    const int cq = tid % TPN;
    const int g  = tid / TPN;
    const int node = base + g;
    if (node >= N_NODES) return;
    float ax = 0.0f, ay = 0.0f, az = 0.0f, aw = 0.0f;
    const float4* sW4 = (const float4*)sW;
#pragma unroll
    for (int k = 0; k < DI; k++) {
        float xv = sX[g][k];
        float4 w4 = sW4[k * TPN + cq];
        ax = fmaf(xv, w4.x, ax); ay = fmaf(xv, w4.y, ay);
        az = fmaf(xv, w4.z, az); aw = fmaf(xv, w4.w, aw);
    }
    union { uint2 u; __half2 h2[2]; } pk;
    pk.h2[0] = __float22half2_rn(make_float2(ax, ay));
    pk.h2[1] = __float22half2_rn(make_float2(az, aw));
    ((uint2*)(Hh + (long)node * DO))[cq] = pk.u;

    float4 as4 = ((const float4*)a_src)[cq];
    float4 ad4 = ((const float4*)a_dst)[cq];
    float ps = ax * as4.x + ay * as4.y + az * as4.z + aw * as4.w;
    float pd = ax * ad4.x + ay * ad4.y + az * ad4.z + aw * ad4.w;
#pragma unroll
    for (int m = TPN / 2; m >= 1; m >>= 1) {
        ps += __shfl_xor(ps, m, TPN);
        pd += __shfl_xor(pd, m, TPN);
    }
    if (cq == 0) { ssrc[node] = ps; sdst[node] = pd; }
}

// ===========================================================================
// Fused: [aggregate layer i (single-pass softmax gather) + bias (+ optional
// raw output) + relu] then [next layer's GEMM + attention projections].
// Masked fully-unrolled chunks maximize independent H-row loads in flight.
// ===========================================================================
template<int DIN, int DOUT>
__global__ void gather_gemm(const __half* __restrict__ Hh_in,
                            const float* __restrict__ ssrc_in,
                            const float* __restrict__ sdst_in,
                            const int* __restrict__ offs,
                            const u16* __restrict__ csr_src,
                            const float* __restrict__ bias_in,
                            int relu_o, float* __restrict__ extra_out,
                            const float* __restrict__ W2,
                            const float* __restrict__ a_src2,
                            const float* __restrict__ a_dst2,
                            __half* __restrict__ Hh_out,
                            float* __restrict__ ssrc2, float* __restrict__ sdst2) {
    const int G = DIN / 4;                           // lanes per node group
    const int NPB = 256 / G;
    constexpr int LDSW = (DOUT > 0) ? DIN * DOUT : 1;
    __shared__ float sW[LDSW];
    if constexpr (DOUT > 0) {
        for (int i = threadIdx.x; i < DIN * DOUT / 4; i += 256)
            ((float4*)sW)[i] = ((const float4*)W2)[i];
        __syncthreads();                             // all 256 threads reach this
    }
    const int t = threadIdx.x;
    const int node = blockIdx.x * NPB + t / G;
    const int r = t % G;                             // uint2 slot within row
    const bool valid = (node < N_NODES);
    const int beg = valid ? offs[node] : 0;
    const int end = valid ? offs[node + 1] : 0;
    const int deg = end - beg;
    const float sdv = valid ? sdst_in[node] : 0.0f;
    const uint2* H2 = (const uint2*)Hh_in;

    // ---- headers for chunks 0 and 1, all loads issued together ----
    int   s0 = 0, s1 = 0;
    float ex0 = 0.0f, ex1 = 0.0f;
    if (r < deg)     s0 = csr_src[beg + r];
    if (G + r < deg) s1 = csr_src[beg + G + r];
    if (r < deg) {
        float v = ssrc_in[s0] + sdv;
        v = (v > 0.0f) ? v : NEG_SLOPE * v;
        ex0 = __expf(v);
    }
    if (G + r < deg) {
        float v = ssrc_in[s1] + sdv;
        v = (v > 0.0f) ? v : NEG_SLOPE * v;
        ex1 = __expf(v);
    }
    float den = ex0 + ex1;
    float4 acc = make_float4(0.0f, 0.0f, 0.0f, 0.0f);

    // ---- chunk 0: masked full unroll (all G loads independent) ----
#pragma unroll
    for (int j = 0; j < G; j++) {
        int   sa = __shfl(s0, j, G);
        float ea = __shfl(ex0, j, G);
        union { uint2 u; __half2 h2[2]; } ua;
        ua.u = H2[(long)sa * G + r];
        float2 a0 = __half22float2(ua.h2[0]), a1 = __half22float2(ua.h2[1]);
        acc.x = fmaf(ea, a0.x, acc.x); acc.y = fmaf(ea, a0.y, acc.y);
        acc.z = fmaf(ea, a1.x, acc.z); acc.w = fmaf(ea, a1.y, acc.w);
    }
    // ---- chunk 1 (only when this group has >G edges) ----
    if (deg > G) {
#pragma unroll
        for (int j = 0; j < G; j++) {
            int   sa = __shfl(s1, j, G);
            float ea = __shfl(ex1, j, G);
            union { uint2 u; __half2 h2[2]; } ua;
            ua.u = H2[(long)sa * G + r];
            float2 a0 = __half22float2(ua.h2[0]), a1 = __half22float2(ua.h2[1]);
            acc.x = fmaf(ea, a0.x, acc.x); acc.y = fmaf(ea, a0.y, acc.y);
            acc.z = fmaf(ea, a1.x, acc.z); acc.w = fmaf(ea, a1.y, acc.w);
        }
    }
    // ---- rare tail chunks (deg > 2G) ----
    for (int cb = beg + 2 * G; cb < end; cb += G) {
        int cnt = min(G, end - cb);
        int s2 = 0; float ex2 = 0.0f;
        if (r < cnt) {
            s2 = csr_src[cb + r];
            float v = ssrc_in[s2] + sdv;
            v = (v > 0.0f) ? v : NEG_SLOPE * v;
            ex2 = __expf(v);
        }
        den += ex2;
#pragma unroll
        for (int j = 0; j < G; j++) {
            int   sa = __shfl(s2, j, G);
            float ea = __shfl(ex2, j, G);
            union { uint2 u; __half2 h2[2]; } ua;
            ua.u = H2[(long)sa * G + r];
            float2 a0 = __half22float2(ua.h2[0]), a1 = __half22float2(ua.h2[1]);
            acc.x = fmaf(ea, a0.x, acc.x); acc.y = fmaf(ea, a0.y, acc.y);
            acc.z = fmaf(ea, a1.x, acc.z); acc.w = fmaf(ea, a1.y, acc.w);
        }
    }
#pragma unroll
    for (int m = G / 2; m >= 1; m >>= 1) den += __shfl_xor(den, m, G);

    float inv = 1.0f / (den + 1e-16f);
    float4 b4 = ((const float4*)bias_in)[r];
    float4 o;
    o.x = acc.x * inv + b4.x; o.y = acc.y * inv + b4.y;
    o.z = acc.z * inv + b4.z; o.w = acc.w * inv + b4.w;
    if (valid && extra_out) ((float4*)extra_out)[(long)node * G + r] = o;  // pre-relu
    if (relu_o) {
        o.x = fmaxf(o.x, 0.0f); o.y = fmaxf(o.y, 0.0f);
        o.z = fmaxf(o.z, 0.0f); o.w = fmaxf(o.w, 0.0f);
    }

    // ---- fused next-layer GEMM + projections ----
    if constexpr (DOUT > 0) {
        constexpr int C = DOUT / (DIN / 4);          // output channels per lane
        float acc2[C];
#pragma unroll
        for (int c = 0; c < C; c++) acc2[c] = 0.0f;
        const int cbase = r * C;
#pragma unroll
        for (int kb = 0; kb < G; kb++) {
            float4 o4;
            o4.x = __shfl(o.x, kb, G);
            o4.y = __shfl(o.y, kb, G);
            o4.z = __shfl(o.z, kb, G);
            o4.w = __shfl(o.w, kb, G);
            const float* wr = &sW[(4 * kb) * DOUT + cbase];
#pragma unroll
            for (int c = 0; c < C; c++) acc2[c] = fmaf(o4.x, wr[c], acc2[c]);
            wr += DOUT;
#pragma unroll
            for (int c = 0; c < C; c++) acc2[c] = fmaf(o4.y, wr[c], acc2[c]);
            wr += DOUT;
#pragma unroll
            for (int c = 0; c < C; c++) acc2[c] = fmaf(o4.z, wr[c], acc2[c]);
            wr += DOUT;
#pragma unroll
            for (int c = 0; c < C; c++) acc2[c] = fmaf(o4.w, wr[c], acc2[c]);
        }
        float ps = 0.0f, pd = 0.0f;
#pragma unroll
        for (int c = 0; c < C; c++) {
            ps = fmaf(acc2[c], a_src2[cbase + c], ps);
            pd = fmaf(acc2[c], a_dst2[cbase + c], pd);
        }
#pragma unroll
        for (int m = G / 2; m >= 1; m >>= 1) {
            ps += __shfl_xor(ps, m, G);
            pd += __shfl_xor(pd, m, G);
        }
        if (valid) {
            union { unsigned int u1; uint2 u2; uint4 u4; __half2 h[C / 2]; } pk;
#pragma unroll
            for (int c = 0; c < C; c += 2)
                pk.h[c / 2] = __float22half2_rn(make_float2(acc2[c], acc2[c + 1]));
            char* dp = (char*)(Hh_out + (long)node * DOUT + cbase);
            if constexpr (C == 2) *(unsigned int*)dp = pk.u1;
            else if constexpr (C == 4) *(uint2*)dp = pk.u2;
            else                        *(uint4*)dp = pk.u4;
            if (r == 0) { ssrc2[node] = ps; sdst2[node] = pd; }
        }
    }
}

extern "C" void kernel_launch(void* const* d_in, const int* in_sizes, int n_in,
                              void* d_out, int out_size, void* d_ws, size_t ws_size,
                              hipStream_t stream) {
    const float* x  = (const float*)d_in[0];
    const int*   ei = (const int*)d_in[1];

    const float* w1  = (const float*)d_in[2];
    const float* as1 = (const float*)d_in[3];
    const float* ad1 = (const float*)d_in[4];
    const float* b1  = (const float*)d_in[5];
    const float* w2  = (const float*)d_in[6];
    const float* as2 = (const float*)d_in[7];
    const float* ad2 = (const float*)d_in[8];
    const float* b2  = (const float*)d_in[9];
    const float* w3  = (const float*)d_in[10];
    const float* as3 = (const float*)d_in[11];
    const float* ad3 = (const float*)d_in[12];
    const float* b3  = (const float*)d_in[13];
    const float* w4  = (const float*)d_in[14];
    const float* as4 = (const float*)d_in[15];
    const float* ad4 = (const float*)d_in[16];
    const float* b4  = (const float*)d_in[17];

    float* out_final = (float*)d_out;                 // [N, 64]
    float* out_h     = (float*)d_out + N_NODES * 64;  // [N, 32] (layer2 pre-relu)

    // workspace layout
    float* ws    = (float*)d_ws;
    __half* Hh_a = (__half*)ws;                 // N*64 halves
    __half* Hh_b = (__half*)(ws + N_NODES * 32);
    float* SS_a  = ws + 2 * N_NODES * 32;       // N
    float* SD_a  = SS_a + N_NODES;              // N
    float* SS_b  = SD_a + N_NODES;              // N
    float* SD_b  = SS_b + N_NODES;              // N
    int* deg     = (int*)(SD_b + N_NODES);      // N ints
    u16* rank    = (u16*)(deg + N_NODES);       // E_TOT u16 (850000 -> even count)
    int* offs    = (int*)(rank + E_TOT);        // N+1 ints
    u16* csr_src = (u16*)(offs + N_NODES + 1);  // E_TOT u16
    int* bsum    = (int*)(csr_src + E_TOT);     // NB_SCAN ints

    const int* src = ei;                // edge_index row 0
    const int* dst = ei + N_EDGES;      // edge_index row 1

    // --- build CSR by dst (once; shared by all 4 layers) ---
    csr_init<<<(N_NODES + 255) / 256, 256, 0, stream>>>(deg);
    csr_degree<<<(E_TOT + 255) / 256, 256, 0, stream>>>(dst, deg, rank);
    scan_p1<<<NB_SCAN, 1024, 0, stream>>>(deg, bsum);
    scan_p3<<<NB_SCAN, 1024, 0, stream>>>(deg, bsum, offs);
    csr_fill<<<(E_TOT + 255) / 256, 256, 0, stream>>>(src, dst, rank, offs, csr_src);

    // --- layer 1 GEMM (reads x), then 4 fused gather[+next-GEMM] stages ---
    gemm_proj<64, 64><<<(N_NODES + 15) / 16, 256, 0, stream>>>(
        x, w1, as1, ad1, Hh_a, SS_a, SD_a);

    // agg L1 (+b1, relu) -> gemm W2 -> L2 frags
    gather_gemm<64, 32><<<(N_NODES * 16 + 255) / 256, 256, 0, stream>>>(
        Hh_a, SS_a, SD_a, offs, csr_src, b1, 1, nullptr,
        w2, as2, ad2, Hh_b, SS_b, SD_b);
    // agg L2 (+b2) -> out_h (pre-relu), relu -> gemm W3 -> L3 frags
    gather_gemm<32, 64><<<(N_NODES * 8 + 255) / 256, 256, 0, stream>>>(
        Hh_b, SS_b, SD_b, offs, csr_src, b2, 1, out_h,
        w3, as3, ad3, Hh_a, SS_a, SD_a);
    // agg L3 (+b3, relu) -> gemm W4 -> L4 frags
    gather_gemm<64, 64><<<(N_NODES * 16 + 255) / 256, 256, 0, stream>>>(
        Hh_a, SS_a, SD_a, offs, csr_src, b3, 1, nullptr,
        w4, as4, ad4, Hh_b, SS_b, SD_b);
    // agg L4 (+b4) -> out_final (no relu, no gemm)
    gather_gemm<64, 0><<<(N_NODES * 16 + 255) / 256, 256, 0, stream>>>(
        Hh_b, SS_b, SD_b, offs, csr_src, b4, 0, out_final,
        nullptr, nullptr, nullptr, nullptr, nullptr, nullptr);
}